// Round 5
// baseline (253.346 us; speedup 1.0000x reference)
//
#include <hip/hip_runtime.h>

typedef _Float16 f16x8 __attribute__((ext_vector_type(8)));
typedef float f32x4 __attribute__((ext_vector_type(4)));

#define B_  8
#define LQ  2048
#define LC  4096
#define DD  256

// Kernel 1: one block per (b, 128-ctx tile, query-half). Converts its own A
// tile f32->f16 into swizzled LDS (ONE barrier total), B query fragments are
// loaded f32 global->VGPR ring (depth-2 prefetch) and converted at use — no
// barriers in the K-loop, so the compiler emits fine-grained per-use vmcnt.
// Writes sp[b][nh][c] = max over this block's 1024 queries. Also zeroes out.
__global__ __launch_bounds__(256, 2)
void gemm_max_kernel(const float* __restrict__ qin, const float* __restrict__ cin,
                     float* __restrict__ sp, float* __restrict__ out) {
    __shared__ __align__(16) _Float16 As[128 * 256];   // 64 KB swizzled A tile
    __shared__ float red[256];

    const int x    = blockIdx.x;     // mt*2 + nh
    const int b    = blockIdx.y;     // batch
    const int mt   = x >> 1;         // context tile 0..31
    const int nh   = x & 1;          // query half
    const int tid  = threadIdx.x;
    const int lane = tid & 63;
    const int wave = tid >> 6;
    const int wm   = wave >> 1;
    const int wn   = wave & 1;
    const int quad = lane >> 4;
    const int l15  = lane & 15;

    if (x == 0) out[b * DD + tid] = 0.f;   // zero for kernel2's atomics

    // ---- stage A tile: f32 global -> f16 -> swizzled LDS.
    // row r, 16B-group kg stored at LDS pos kg holds global group
    // (kg&16)|((kg&15)^(r&15))  (self-inverse swizzle).
    {
        const float* Ag = cin + ((size_t)b * LC + (size_t)mt * 128) * DD;
        const int rsub = tid >> 5;         // 0..7
        const int kg   = tid & 31;
#pragma unroll
        for (int p = 0; p < 16; ++p) {
            const int row = p * 8 + rsub;
            const int kgg = (kg & 16) | ((kg & 15) ^ (row & 15));
            const float* s = Ag + (size_t)row * DD + kgg * 8;
            const float4 v0 = *(const float4*)(s);
            const float4 v1 = *(const float4*)(s + 4);
            f16x8 o;
            o[0] = (_Float16)v0.x; o[1] = (_Float16)v0.y;
            o[2] = (_Float16)v0.z; o[3] = (_Float16)v0.w;
            o[4] = (_Float16)v1.x; o[5] = (_Float16)v1.y;
            o[6] = (_Float16)v1.z; o[7] = (_Float16)v1.w;
            *(f16x8*)((char*)As + row * 512 + kg * 16) = o;
        }
    }
    __syncthreads();   // the only barrier before the epilogue

    // ---- B raw-f32 register ring, depth 2: slot = s&1.
    const float* Bbase = qin +
        ((size_t)b * LQ + (size_t)nh * 1024 + (size_t)(wn * 64 + l15)) * DD + quad * 8;
    f32x4 raw[2][4][2];
    #define BLOAD(s, slot)                                                        \
        {                                                                         \
            const float* _p = Bbase + (size_t)((s) >> 3) * (128 * DD)             \
                                    + ((s) & 7) * 32;                             \
            _Pragma("unroll")                                                     \
            for (int ni = 0; ni < 4; ++ni) {                                      \
                raw[slot][ni][0] = *(const f32x4*)(_p + (size_t)ni * 16 * DD);    \
                raw[slot][ni][1] = *(const f32x4*)(_p + (size_t)ni * 16 * DD + 4);\
            }                                                                     \
        }
    BLOAD(0, 0)
    BLOAD(1, 1)

    float rm[4][4];
#pragma unroll
    for (int mi = 0; mi < 4; ++mi)
#pragma unroll
        for (int r = 0; r < 4; ++r)
            rm[mi][r] = -3.4e38f;

#pragma unroll 1
    for (int nt = 0; nt < 8; ++nt) {
        f32x4 acc[4][4];
#pragma unroll
        for (int mi = 0; mi < 4; ++mi)
#pragma unroll
            for (int ni = 0; ni < 4; ++ni)
                acc[mi][ni] = (f32x4)0.0f;

#pragma unroll
        for (int ksl = 0; ksl < 8; ++ksl) {
            const int s = nt * 8 + ksl;
            // convert this step's raw f32 -> f16 fragments (VALU, hides under MFMA)
            f16x8 bfr[4];
#pragma unroll
            for (int ni = 0; ni < 4; ++ni) {
                f16x8 o;
#pragma unroll
                for (int e = 0; e < 4; ++e) {
                    o[e]     = (_Float16)raw[s & 1][ni][0][e];
                    o[e + 4] = (_Float16)raw[s & 1][ni][1][e];
                }
                bfr[ni] = o;
            }
            if (s + 2 < 64) BLOAD(s + 2, s & 1)   // refill the slot just consumed

            f16x8 afr[4];
            const int kg = ksl * 4 + quad;
#pragma unroll
            for (int mi = 0; mi < 4; ++mi) {
                const int row = wm * 64 + mi * 16 + l15;
                const int pos = (kg & 16) | ((kg & 15) ^ (row & 15));
                afr[mi] = *(const f16x8*)((const char*)As + row * 512 + pos * 16);
            }
#pragma unroll
            for (int mi = 0; mi < 4; ++mi)
#pragma unroll
                for (int ni = 0; ni < 4; ++ni)
                    acc[mi][ni] = __builtin_amdgcn_mfma_f32_16x16x32_f16(
                        afr[mi], bfr[ni], acc[mi][ni], 0, 0, 0);
        }
#pragma unroll
        for (int mi = 0; mi < 4; ++mi)
#pragma unroll
            for (int r = 0; r < 4; ++r)
                rm[mi][r] = fmaxf(rm[mi][r],
                                  fmaxf(fmaxf(acc[mi][0][r], acc[mi][1][r]),
                                        fmaxf(acc[mi][2][r], acc[mi][3][r])));
    }
    #undef BLOAD

    // reduce over the 16 query-col lanes, then across the two wn halves
#pragma unroll
    for (int sh = 1; sh <= 8; sh <<= 1)
#pragma unroll
        for (int mi = 0; mi < 4; ++mi)
#pragma unroll
            for (int r = 0; r < 4; ++r)
                rm[mi][r] = fmaxf(rm[mi][r], __shfl_xor(rm[mi][r], sh, 64));

    if (l15 == 0) {
#pragma unroll
        for (int mi = 0; mi < 4; ++mi)
#pragma unroll
            for (int r = 0; r < 4; ++r)
                red[wn * 128 + wm * 64 + mi * 16 + quad * 4 + r] = rm[mi][r];
    }
    __syncthreads();
    if (tid < 128)
        sp[((size_t)b * 2 + nh) * LC + mt * 128 + tid] =
            fmaxf(red[tid], red[128 + tid]);
}

// Kernel 2: 512 blocks. Each block redundantly computes the batch softmax
// stats from sp (32 KB), then its own 64-context slice of the weighted sum
// reading f32 context at 16 B/lane, one atomicAdd per output element.
__global__ __launch_bounds__(256)
void softmax_out_kernel(const float* __restrict__ sp, const float* __restrict__ cin,
                        float* __restrict__ out) {
    __shared__ float pr[4096];
    __shared__ float part[4][256];
    __shared__ float rsc[8];

    const int ch   = blockIdx.x;   // 0..63
    const int b    = blockIdx.y;   // 0..7
    const int tid  = threadIdx.x;
    const int lane = tid & 63;
    const int wave = tid >> 6;

    float sv[16];
    float lmax = -3.4e38f;
#pragma unroll
    for (int j = 0; j < 16; ++j) {
        const int c = j * 256 + tid;
        const float v = fmaxf(sp[((size_t)b * 2 + 0) * LC + c],
                              sp[((size_t)b * 2 + 1) * LC + c]);
        sv[j] = v;
        lmax  = fmaxf(lmax, v);
    }
#pragma unroll
    for (int sh = 1; sh < 64; sh <<= 1)
        lmax = fmaxf(lmax, __shfl_xor(lmax, sh, 64));
    if (lane == 0) rsc[wave] = lmax;
    __syncthreads();
    const float M = fmaxf(fmaxf(rsc[0], rsc[1]), fmaxf(rsc[2], rsc[3]));

    float lsum = 0.f;
#pragma unroll
    for (int j = 0; j < 16; ++j) {
        const float e = __expf(sv[j] - M);
        pr[j * 256 + tid] = e;
        lsum += e;
    }
#pragma unroll
    for (int sh = 1; sh < 64; sh <<= 1)
        lsum += __shfl_xor(lsum, sh, 64);
    if (lane == 0) rsc[4 + wave] = lsum;
    __syncthreads();                 // pr[] complete + partial sums visible
    const float inv = 1.f / (rsc[4] + rsc[5] + rsc[6] + rsc[7]);

    // weighted partial over ctx rows [ch*64, ch*64+64): group g = tid>>6 takes
    // rows g, g+4, ...; each lane covers 4 consecutive d columns (float4).
    const int g = wave;
    const float* cb = cin + ((size_t)b * LC + (size_t)ch * 64) * DD + lane * 4;
    const float* pb = pr + ch * 64;
    f32x4 acc = (f32x4)0.0f;
#pragma unroll 4
    for (int i = g; i < 64; i += 4) {
        const f32x4 v = *(const f32x4*)(cb + (size_t)i * DD);
        acc += pb[i] * v;
    }
#pragma unroll
    for (int e = 0; e < 4; ++e) part[g][lane * 4 + e] = acc[e];
    __syncthreads();
    atomicAdd(&out[b * DD + tid],
              (part[0][tid] + part[1][tid] + part[2][tid] + part[3][tid]) * inv);
}

extern "C" void kernel_launch(void* const* d_in, const int* in_sizes, int n_in,
                              void* d_out, int out_size, void* d_ws, size_t ws_size,
                              hipStream_t stream) {
    const float* q   = (const float*)d_in[0];   // [8, 2048, 256] f32
    const float* ctx = (const float*)d_in[1];   // [8, 4096, 256] f32
    float* out = (float*)d_out;                 // [8, 1, 256] f32

    float* sp = (float*)d_ws;                   // [8][2][4096] partial maxes, 256 KB

    gemm_max_kernel<<<dim3(64, 8), 256, 0, stream>>>(q, ctx, sp, out);
    softmax_out_kernel<<<dim3(64, 8), 256, 0, stream>>>(sp, ctx, out);
}

// Round 6
// 160.337 us; speedup vs baseline: 1.5801x; 1.5801x over previous
//
#include <hip/hip_runtime.h>

typedef _Float16 f16x8 __attribute__((ext_vector_type(8)));
typedef float f32x4 __attribute__((ext_vector_type(4)));
typedef float f32x16 __attribute__((ext_vector_type(16)));

#define B_  8
#define LQ  2048
#define LC  4096
#define DD  256

// s_waitcnt immediates (gfx9 encoding: vmcnt[3:0]@0, expcnt@4, lgkmcnt@8, vmcnt[5:4]@14)
#define WAIT_VM8   0x0F78   // vmcnt<=8, lgkm/exp don't-care
#define WAIT_VM0   0x0F70   // vmcnt==0
#define WAIT_LGKM0 0xC07F   // lgkmcnt==0, vmcnt don't-care

// async global->LDS, 16B per lane (wave-uniform base + lane*16; per-lane ptr form
// validated correct in rounds 1-3)
__device__ __forceinline__ void gload_lds16(const void* g, void* l) {
    __builtin_amdgcn_global_load_lds(
        (const __attribute__((address_space(1))) unsigned int*)g,
        (__attribute__((address_space(3))) unsigned int*)l,
        16, 0, 0);
}

// f32 -> f16 convert of query only (8 floats/thread, exact coverage).
__global__ __launch_bounds__(256)
void convert_q(const float* __restrict__ q, _Float16* __restrict__ qf) {
    const size_t i = ((size_t)blockIdx.x * 256 + threadIdx.x) * 8;
    const f32x4 v0 = *(const f32x4*)(q + i);
    const f32x4 v1 = *(const f32x4*)(q + i + 4);
    f16x8 o;
#pragma unroll
    for (int e = 0; e < 4; ++e) { o[e] = (_Float16)v0[e]; o[e + 4] = (_Float16)v1[e]; }
    *(f16x8*)(qf + i) = o;
}

// One block per (b, 128-ctx tile, 1024-query half). 4 waves: wm = ctx 64-half,
// wn = query 64-half within each 128-q tile. 32x32x16 f16 MFMA.
// A (context): f32 global -> convert -> af[2][16] VGPRs, resident for K=256.
// B (query): per-WAVE private LDS ring (2 slots x 8KB), global_load_lds + explicit
// vmcnt waits — ZERO barriers in the K-loop (vmcnt is per-wave; slots are private).
// Writes sp[b][nh][c] = max over this block's 1024 queries. x==0 blocks zero out.
__global__ __launch_bounds__(256, 2)
void gemm_max_kernel(const _Float16* __restrict__ qf, const float* __restrict__ ctx,
                     float* __restrict__ sp, float* __restrict__ out) {
    __shared__ __align__(16) _Float16 Ring[4][2][4096];   // [wave][slot][64 rows x 64 halfs]
    __shared__ float red[256];                            // [wn][128] running row-max

    const int x     = blockIdx.x;    // mt*2 + nh
    const int b     = blockIdx.y;
    const int mt    = x >> 1;
    const int nh    = x & 1;
    const int tid   = threadIdx.x;
    const int lane  = tid & 63;
    const int wave  = tid >> 6;
    const int wm    = wave >> 1;
    const int wn    = wave & 1;
    const int l31   = lane & 31;
    const int lhalf = lane >> 5;

    if (x == 0) out[b * DD + tid] = 0.f;

    // ---- A prologue: ctx f32 -> f16 fragments in VGPRs.
    // 32x32x16 A-frag: m = lane&31, k = (lane>>5)*8 + j; af[ti][ks] covers k = ks*16.
    f16x8 af[2][16];
    {
        const float* Abase = ctx + ((size_t)(b * LC + mt * 128 + wm * 64)) * DD + lhalf * 8;
#pragma unroll
        for (int ti = 0; ti < 2; ++ti) {
            const float* rp = Abase + (size_t)(ti * 32 + l31) * DD;
#pragma unroll
            for (int ks = 0; ks < 16; ++ks) {
                const f32x4 u0 = *(const f32x4*)(rp + ks * 16);
                const f32x4 u1 = *(const f32x4*)(rp + ks * 16 + 4);
                f16x8 o;
#pragma unroll
                for (int e = 0; e < 4; ++e) { o[e] = (_Float16)u0[e]; o[e + 4] = (_Float16)u1[e]; }
                af[ti][ks] = o;
            }
        }
    }

    red[tid] = -3.4e38f;
    __syncthreads();   // red init visible; A loads already drained by the converts

    // ---- B ring staging. Chunk s = nt*4+kc: q rows [nh*1024 + nt*128 + wn*64, +64),
    // k halfs [kc*64, +64). XOR swizzle: row r group slot g holds global group g^(r&7).
    const int srow = lane >> 3;                 // 0..7 (row-within-pass)
    const int sgk  = (lane & 7) ^ srow;         // fetched global 16B-group
    const _Float16* Qw = qf + ((size_t)(b * LQ + nh * 1024 + wn * 64)) * DD;

    #define STAGE_B(nt_, kc_, slot_)                                              \
        {                                                                         \
            const _Float16* _s = Qw + (size_t)((nt_) * 128 + srow) * DD           \
                                    + (kc_) * 64 + sgk * 8;                       \
            char* _d = (char*)&Ring[wave][slot_][0] + lane * 16;                  \
            _Pragma("unroll")                                                     \
            for (int p = 0; p < 8; ++p)                                           \
                gload_lds16(_s + (size_t)p * 8 * DD, _d + p * 1024);              \
        }

    STAGE_B(0, 0, 0)   // s=0
    STAGE_B(0, 1, 1)   // s=1

#pragma unroll 1
    for (int nt = 0; nt < 8; ++nt) {
        f32x16 acc[2][2];
#pragma unroll
        for (int ti = 0; ti < 2; ++ti)
#pragma unroll
            for (int ni = 0; ni < 2; ++ni)
                acc[ti][ni] = (f32x16)0.0f;

#pragma unroll
        for (int kc = 0; kc < 4; ++kc) {
            // wait: chunk s=nt*4+kc landed (newest 8 = next chunk's stage stay in flight)
            if (kc < 2)      __builtin_amdgcn_s_waitcnt(WAIT_VM8);
            else if (nt < 7) __builtin_amdgcn_s_waitcnt(WAIT_VM8);
            else             __builtin_amdgcn_s_waitcnt(WAIT_VM0);   // tail chunks 30,31
            __builtin_amdgcn_sched_barrier(0);

#pragma unroll
            for (int ks = 0; ks < 4; ++ks) {
                f16x8 bf[2];
#pragma unroll
                for (int ni = 0; ni < 2; ++ni) {
                    const int row = ni * 32 + l31;
                    const int pos = (ks * 2 + lhalf) ^ (row & 7);
                    bf[ni] = *(const f16x8*)&Ring[wave][kc & 1][row * 64 + pos * 8];
                }
#pragma unroll
                for (int ti = 0; ti < 2; ++ti)
#pragma unroll
                    for (int ni = 0; ni < 2; ++ni)
                        acc[ti][ni] = __builtin_amdgcn_mfma_f32_32x32x16_f16(
                            af[ti][kc * 4 + ks], bf[ni], acc[ti][ni], 0, 0, 0);
            }

            // all ds_reads of this slot retired before refilling it
            __builtin_amdgcn_s_waitcnt(WAIT_LGKM0);
            __builtin_amdgcn_sched_barrier(0);
            const int s2 = nt * 4 + kc + 2;
            if (s2 < 32) STAGE_B(s2 >> 2, s2 & 3, kc & 1)
        }

        // ---- per-nt epilogue: max over this tile's 128 q cols.
        // C/D 32x32: col = lane&31, row = (reg&3) + 8*(reg>>2) + 4*lhalf.
        float v[2][16];
#pragma unroll
        for (int ti = 0; ti < 2; ++ti)
#pragma unroll
            for (int r = 0; r < 16; ++r) {
                float m = fmaxf(acc[ti][0][r], acc[ti][1][r]);
#pragma unroll
                for (int sh = 1; sh <= 16; sh <<= 1)
                    m = fmaxf(m, __shfl_xor(m, sh, 64));
                v[ti][r] = m;
            }
        if (l31 == 0) {
#pragma unroll
            for (int ti = 0; ti < 2; ++ti)
#pragma unroll
                for (int r = 0; r < 16; ++r) {
                    const int row = wm * 64 + ti * 32 + lhalf * 4 + (r & 3) + 8 * (r >> 2);
                    red[wn * 128 + row] = fmaxf(red[wn * 128 + row], v[ti][r]);
                }
        }
    }
    #undef STAGE_B

    __syncthreads();
    if (tid < 128)
        sp[((size_t)b * 2 + nh) * LC + mt * 128 + tid] =
            fmaxf(red[tid], red[128 + tid]);
}

// 256 blocks: each redundantly computes batch softmax stats from sp, then a
// 128-context slice of the weighted sum (f32 ctx, fully coalesced), atomicAdd.
__global__ __launch_bounds__(256)
void softmax_out_kernel(const float* __restrict__ sp, const float* __restrict__ ctx,
                        float* __restrict__ out) {
    __shared__ float pr[128];
    __shared__ float part[4][256];
    __shared__ float rsc[8];

    const int ch   = blockIdx.x;   // 0..31
    const int b    = blockIdx.y;
    const int tid  = threadIdx.x;
    const int lane = tid & 63;
    const int wave = tid >> 6;
    const float* sp0 = sp + (size_t)b * 2 * LC;
    const float* sp1 = sp0 + LC;

    float sv[16];
    float lmax = -3.4e38f;
#pragma unroll
    for (int j = 0; j < 16; ++j) {
        const int c = j * 256 + tid;
        sv[j] = fmaxf(sp0[c], sp1[c]);
        lmax  = fmaxf(lmax, sv[j]);
    }
#pragma unroll
    for (int sh = 1; sh < 64; sh <<= 1)
        lmax = fmaxf(lmax, __shfl_xor(lmax, sh, 64));
    if (lane == 0) rsc[wave] = lmax;
    __syncthreads();
    const float M = fmaxf(fmaxf(rsc[0], rsc[1]), fmaxf(rsc[2], rsc[3]));

    float lsum = 0.f;
#pragma unroll
    for (int j = 0; j < 16; ++j) lsum += __expf(sv[j] - M);
#pragma unroll
    for (int sh = 1; sh < 64; sh <<= 1)
        lsum += __shfl_xor(lsum, sh, 64);
    if (lane == 0) rsc[4 + wave] = lsum;
    if (tid < 128) {
        const int c = ch * 128 + tid;
        pr[tid] = __expf(fmaxf(sp0[c], sp1[c]) - M);
    }
    __syncthreads();
    const float inv = 1.f / (rsc[4] + rsc[5] + rsc[6] + rsc[7]);

    // rows [ch*128, +128): wave w takes rows w, w+4, ...; lane covers 4 d-cols.
    const float* cb = ctx + ((size_t)(b * LC + ch * 128)) * DD + lane * 4;
    f32x4 acc = (f32x4)0.0f;
#pragma unroll 8
    for (int i = wave; i < 128; i += 4)
        acc += pr[i] * *(const f32x4*)(cb + (size_t)i * DD);
#pragma unroll
    for (int e = 0; e < 4; ++e) part[wave][lane * 4 + e] = acc[e];
    __syncthreads();
    atomicAdd(&out[b * DD + tid],
              (part[0][tid] + part[1][tid] + part[2][tid] + part[3][tid]) * inv);
}

extern "C" void kernel_launch(void* const* d_in, const int* in_sizes, int n_in,
                              void* d_out, int out_size, void* d_ws, size_t ws_size,
                              hipStream_t stream) {
    const float* q   = (const float*)d_in[0];   // [8, 2048, 256] f32
    const float* ctx = (const float*)d_in[1];   // [8, 4096, 256] f32
    float* out = (float*)d_out;                 // [8, 1, 256] f32

    // ws: qf @0 (8,388,608 B), sp @8388608 (8*2*4096*4 = 262,144 B)
    char* ws = (char*)d_ws;
    _Float16* qf = (_Float16*)(ws);
    float* sp    = (float*)(ws + 8388608);

    convert_q<<<2048, 256, 0, stream>>>(q, qf);
    gemm_max_kernel<<<dim3(64, 8), 256, 0, stream>>>(qf, ctx, sp, out);
    softmax_out_kernel<<<dim3(32, 8), 256, 0, stream>>>(sp, ctx, out);
}